// Round 3
// baseline (2251.611 us; speedup 1.0000x reference)
//
#include <hip/hip_runtime.h>
#include <math.h>

#define B_  4
#define S_  2048
#define D_  1024
#define H_  16
#define DH_ 64
#define M_  (B_*S_)          // 8192
#define LN_EPS 1e-6f

typedef __attribute__((ext_vector_type(4))) float f32x4;
typedef __attribute__((ext_vector_type(8))) short s16x8;   // 8 bf16 = 4 VGPRs

// ---------------- async global->LDS, 16 B per lane --------------------------
__device__ __forceinline__ void gl16(const void* g, void* l) {
  __builtin_amdgcn_global_load_lds(
      (const __attribute__((address_space(1))) unsigned int*)g,
      (__attribute__((address_space(3))) unsigned int*)l, 16, 0, 0);
}

// ---------------- fp32 -> bf16(hi) + bf16(lo) split (truncation) ------------
__device__ __forceinline__ void split2(float x, ushort& h, ushort& l) {
  unsigned u = __float_as_uint(x);
  h = (ushort)(u >> 16);
  float r = x - __uint_as_float(u & 0xFFFF0000u);   // exact
  l = (ushort)(__float_as_uint(r) >> 16);
}

// Elementwise split: in [n] fp32 -> hi,lo [n] bf16. 8 elems/thread.
__global__ __launch_bounds__(256) void split_kernel(
    const float* __restrict__ in, ushort* __restrict__ hi, ushort* __restrict__ lo)
{
  const size_t t = (size_t)blockIdx.x * 256 + threadIdx.x;
  const float4 a = *(const float4*)(in + t * 8);
  const float4 b = *(const float4*)(in + t * 8 + 4);
  s16x8 hv, lv;
  ushort h, l;
  split2(a.x, h, l); hv[0] = (short)h; lv[0] = (short)l;
  split2(a.y, h, l); hv[1] = (short)h; lv[1] = (short)l;
  split2(a.z, h, l); hv[2] = (short)h; lv[2] = (short)l;
  split2(a.w, h, l); hv[3] = (short)h; lv[3] = (short)l;
  split2(b.x, h, l); hv[4] = (short)h; lv[4] = (short)l;
  split2(b.y, h, l); hv[5] = (short)h; lv[5] = (short)l;
  split2(b.z, h, l); hv[6] = (short)h; lv[6] = (short)l;
  split2(b.w, h, l); hv[7] = (short)h; lv[7] = (short)l;
  *(s16x8*)(hi + t * 8) = hv;
  *(s16x8*)(lo + t * 8) = lv;
}

// Transpose + split: W [K=1024][N=1024] fp32 -> hiT,loT [N][K] bf16.
__global__ __launch_bounds__(256) void splitT_kernel(
    const float* __restrict__ W, ushort* __restrict__ hiT, ushort* __restrict__ loT)
{
  __shared__ float tile[64][65];
  const int n0 = blockIdx.x * 64, k0 = blockIdx.y * 64;
  const int tid = threadIdx.x;
  #pragma unroll
  for (int i = 0; i < 4; ++i) {
    int c = tid + (i << 8);
    int r = c >> 4;
    int c4 = (c & 15) << 2;
    float4 v = *(const float4*)(W + (size_t)(k0 + r) * D_ + n0 + c4);
    tile[r][c4+0] = v.x; tile[r][c4+1] = v.y; tile[r][c4+2] = v.z; tile[r][c4+3] = v.w;
  }
  __syncthreads();
  #pragma unroll
  for (int i = 0; i < 4; ++i) {
    int c = tid + (i << 8);
    int n = c >> 4;
    int k4 = (c & 15) << 2;
    ushort h0,h1,h2,h3, l0,l1,l2,l3;
    split2(tile[k4+0][n], h0, l0);
    split2(tile[k4+1][n], h1, l1);
    split2(tile[k4+2][n], h2, l2);
    split2(tile[k4+3][n], h3, l3);
    size_t o = (size_t)(n0 + n) * D_ + k0 + k4;
    *(ushort4*)(hiT + o) = make_ushort4(h0, h1, h2, h3);
    *(ushort4*)(loT + o) = make_ushort4(l0, l1, l2, l3);
  }
}

// Transpose bf16 V per head: [b][s][D] (head-interleaved) -> [b][h][64][S]
__global__ __launch_bounds__(256) void vtrans_kernel(
    const ushort* __restrict__ Vhi, const ushort* __restrict__ Vlo,
    ushort* __restrict__ Vthi, ushort* __restrict__ Vtlo)
{
  __shared__ ushort Th[64][72], Tl[64][72];
  const int st = blockIdx.x, h = blockIdx.y, b = blockIdx.z;
  const int s0 = st * 64;
  const int tid = threadIdx.x;
  const ushort* sh = Vhi + ((size_t)(b*S_ + s0)) * D_ + h * DH_;
  const ushort* sl = Vlo + ((size_t)(b*S_ + s0)) * D_ + h * DH_;
  #pragma unroll
  for (int i = 0; i < 4; ++i) {
    int idx = tid + (i << 8);
    int r = idx >> 4, c4 = (idx & 15) << 2;   // r=s-local, c4=d-local
    *(ushort4*)&Th[r][c4] = *(const ushort4*)(sh + (size_t)r * D_ + c4);
    *(ushort4*)&Tl[r][c4] = *(const ushort4*)(sl + (size_t)r * D_ + c4);
  }
  __syncthreads();
  ushort* dh = Vthi + ((size_t)(b*H_ + h)) * DH_ * S_ + s0;
  ushort* dl = Vtlo + ((size_t)(b*H_ + h)) * DH_ * S_ + s0;
  #pragma unroll
  for (int i = 0; i < 4; ++i) {
    int idx = tid + (i << 8);
    int d = idx >> 4, s4 = (idx & 15) << 2;
    ushort4 oh = make_ushort4(Th[s4+0][d], Th[s4+1][d], Th[s4+2][d], Th[s4+3][d]);
    ushort4 ol = make_ushort4(Tl[s4+0][d], Tl[s4+1][d], Tl[s4+2][d], Tl[s4+3][d]);
    *(ushort4*)(dh + (size_t)d * S_ + s4) = oh;
    *(ushort4*)(dl + (size_t)d * S_ + s4) = ol;
  }
}

// ---------------- bf16x3 MFMA GEMM, global_load_lds staged ------------------
// C = A@B (+bias) (+resid). Out: fp32 C, or bf16 split (Chi/Clo) if Chi!=0.
__global__ __launch_bounds__(256) void gemm_mfma_kernel(
    const ushort* __restrict__ Ahi, const ushort* __restrict__ Alo,
    const ushort* __restrict__ BThi, const ushort* __restrict__ BTlo,
    const float* __restrict__ bias, const float* __restrict__ resid,
    float* __restrict__ C, ushort* __restrict__ Chi, ushort* __restrict__ Clo,
    int M, int N, int K)
{
  __shared__ ushort Ah[128][32], Al[128][32], Bh[128][32], Bl[128][32];
  const int tid  = threadIdx.x;
  const int lane = tid & 63;
  const int wid  = tid >> 6;
  const int wm   = wid >> 1, wn = wid & 1;
  const int bm = blockIdx.y * 128, bn = blockIdx.x * 128;

  // staging chunks: j0/j1 in [0,512), row=j>>2 (0..127), kc=(j&3)*8 elems
  const int j0 = wid * 128 + lane, j1 = j0 + 64;
  const int r0 = j0 >> 2, kc0 = (j0 & 3) << 3;
  const int r1 = j1 >> 2, kc1 = (j1 & 3) << 3;
  const unsigned off0 = (unsigned)(wid * 128) * 16;      // wave-uniform LDS byte
  const unsigned off1 = off0 + 1024;

  const ushort* a0 = Ahi  + (size_t)(bm + r0) * K + kc0;
  const ushort* a1 = Ahi  + (size_t)(bm + r1) * K + kc1;
  const ushort* c0 = Alo  + (size_t)(bm + r0) * K + kc0;
  const ushort* c1 = Alo  + (size_t)(bm + r1) * K + kc1;
  const ushort* b0 = BThi + (size_t)(bn + r0) * K + kc0;
  const ushort* b1 = BThi + (size_t)(bn + r1) * K + kc1;
  const ushort* d0p = BTlo + (size_t)(bn + r0) * K + kc0;
  const ushort* d1p = BTlo + (size_t)(bn + r1) * K + kc1;

  f32x4 acc[4][4] = {};
  const int kf = (lane >> 4) << 3;
  const int fm = wm * 64 + (lane & 15);
  const int fn = wn * 64 + (lane & 15);

  for (int k0 = 0; k0 < K; k0 += 32) {
    gl16(a0 + k0, (char*)&Ah[0][0] + off0);
    gl16(a1 + k0, (char*)&Ah[0][0] + off1);
    gl16(c0 + k0, (char*)&Al[0][0] + off0);
    gl16(c1 + k0, (char*)&Al[0][0] + off1);
    gl16(b0 + k0, (char*)&Bh[0][0] + off0);
    gl16(b1 + k0, (char*)&Bh[0][0] + off1);
    gl16(d0p + k0, (char*)&Bl[0][0] + off0);
    gl16(d1p + k0, (char*)&Bl[0][0] + off1);
    __syncthreads();
    s16x8 ah[4], al[4], bh[4], bl[4];
    #pragma unroll
    for (int i = 0; i < 4; ++i) {
      ah[i] = *(const s16x8*)&Ah[fm + i*16][kf];
      al[i] = *(const s16x8*)&Al[fm + i*16][kf];
      bh[i] = *(const s16x8*)&Bh[fn + i*16][kf];
      bl[i] = *(const s16x8*)&Bl[fn + i*16][kf];
    }
    #pragma unroll
    for (int mi = 0; mi < 4; ++mi) {
      #pragma unroll
      for (int ni = 0; ni < 4; ++ni) {
        acc[mi][ni] = __builtin_amdgcn_mfma_f32_16x16x32_bf16(ah[mi], bh[ni], acc[mi][ni], 0, 0, 0);
        acc[mi][ni] = __builtin_amdgcn_mfma_f32_16x16x32_bf16(al[mi], bh[ni], acc[mi][ni], 0, 0, 0);
        acc[mi][ni] = __builtin_amdgcn_mfma_f32_16x16x32_bf16(ah[mi], bl[ni], acc[mi][ni], 0, 0, 0);
      }
    }
    __syncthreads();
  }
  const int rbase = bm + wm*64 + ((lane >> 4) << 2);
  #pragma unroll
  for (int ni = 0; ni < 4; ++ni) {
    const int col = bn + wn*64 + ni*16 + (lane & 15);
    const float bb = bias[col];
    #pragma unroll
    for (int mi = 0; mi < 4; ++mi) {
      #pragma unroll
      for (int j = 0; j < 4; ++j) {
        const int row = rbase + mi*16 + j;
        float v = acc[mi][ni][j] + bb;
        const size_t off = (size_t)row * N + col;
        if (Chi) {
          ushort h, l; split2(v, h, l);
          Chi[off] = h; Clo[off] = l;
        } else {
          if (resid) v += resid[off];
          C[off] = v;
        }
      }
    }
  }
}

// ---------------- block-wide all-reduce (256 threads = 4 waves of 64) -------
__device__ __forceinline__ float block_allreduce(float v, bool is_max, float* sbuf) {
  #pragma unroll
  for (int o = 32; o > 0; o >>= 1) {
    float other = __shfl_down(v, o, 64);
    v = is_max ? fmaxf(v, other) : (v + other);
  }
  __syncthreads();
  if ((threadIdx.x & 63) == 0) sbuf[threadIdx.x >> 6] = v;
  __syncthreads();
  float r = sbuf[0];
  #pragma unroll
  for (int w = 1; w < 4; ++w) r = is_max ? fmaxf(r, sbuf[w]) : (r + sbuf[w]);
  return r;
}

// ---------------- scores (MFMA bf16x3), gload_lds staged --------------------
// Tile 128 q x 64 k. Operands pre-split bf16 in global.
__global__ __launch_bounds__(256) void scores_mfma_kernel(
    const ushort* __restrict__ Qhi, const ushort* __restrict__ Qlo,
    const ushort* __restrict__ Khi, const ushort* __restrict__ Klo,
    float* __restrict__ Wout)
{
  const int kt = blockIdx.x;             // 0..31
  const int qt = blockIdx.y;             // 0..15
  if (kt > 2*qt + 1) return;             // fully masked
  const int bh = blockIdx.z;
  const int b = bh >> 4, h = bh & 15;
  const int q0 = qt * 128, k0 = kt * 64;
  __shared__ ushort Qh2[2][128][32], Ql2[2][128][32];
  __shared__ ushort Kh2[2][64][32],  Kl2[2][64][32];
  const int tid = threadIdx.x;
  const int lane = tid & 63, wid = tid >> 6;
  const int wm = wid >> 1, wn = wid & 1;   // wave tile: 64 q x 32 k
  const ushort* qh = Qhi + ((size_t)(b*S_ + q0)) * D_ + h * DH_;
  const ushort* ql = Qlo + ((size_t)(b*S_ + q0)) * D_ + h * DH_;
  const ushort* kh = Khi + ((size_t)(b*S_ + k0)) * D_ + h * DH_;
  const ushort* kl = Klo + ((size_t)(b*S_ + k0)) * D_ + h * DH_;
  // Q: 1024 chunks/array, 4 per thread: jj = wid*256 + i*64 + lane
  #pragma unroll
  for (int i = 0; i < 4; ++i) {
    int jj = wid * 256 + i * 64 + lane;
    int row = (jj >> 2) & 127;
    int d = ((jj >> 9) << 5) + ((jj & 3) << 3);   // half*32 + cc*8
    unsigned lb = (unsigned)(wid * 256 + i * 64 - lane) * 16 + (unsigned)lane * 16; // = jj*16
    gl16(qh + (size_t)row * D_ + d, (char*)&Qh2[0][0][0] + (unsigned)(jj - lane) * 16);
    gl16(ql + (size_t)row * D_ + d, (char*)&Ql2[0][0][0] + (unsigned)(jj - lane) * 16);
    (void)lb;
  }
  // K: 512 chunks/array, 2 per thread: jj = wid*128 + i*64 + lane
  #pragma unroll
  for (int i = 0; i < 2; ++i) {
    int jj = wid * 128 + i * 64 + lane;
    int row = (jj >> 2) & 63;
    int d = ((jj >> 8) << 5) + ((jj & 3) << 3);
    gl16(kh + (size_t)row * D_ + d, (char*)&Kh2[0][0][0] + (unsigned)(jj - lane) * 16);
    gl16(kl + (size_t)row * D_ + d, (char*)&Kl2[0][0][0] + (unsigned)(jj - lane) * 16);
  }
  __syncthreads();
  const int kf = (lane >> 4) << 3;
  const int fm = wm * 64 + (lane & 15);
  const int fn = wn * 32 + (lane & 15);
  f32x4 acc[4][2] = {};
  #pragma unroll
  for (int hd = 0; hd < 2; ++hd) {
    s16x8 qa[4], qb[4], ka[2], kb[2];
    #pragma unroll
    for (int mi = 0; mi < 4; ++mi) {
      qa[mi] = *(const s16x8*)&Qh2[hd][fm + mi*16][kf];
      qb[mi] = *(const s16x8*)&Ql2[hd][fm + mi*16][kf];
    }
    #pragma unroll
    for (int ni = 0; ni < 2; ++ni) {
      ka[ni] = *(const s16x8*)&Kh2[hd][fn + ni*16][kf];
      kb[ni] = *(const s16x8*)&Kl2[hd][fn + ni*16][kf];
    }
    #pragma unroll
    for (int mi = 0; mi < 4; ++mi) {
      #pragma unroll
      for (int ni = 0; ni < 2; ++ni) {
        acc[mi][ni] = __builtin_amdgcn_mfma_f32_16x16x32_bf16(qa[mi], ka[ni], acc[mi][ni], 0, 0, 0);
        acc[mi][ni] = __builtin_amdgcn_mfma_f32_16x16x32_bf16(qb[mi], ka[ni], acc[mi][ni], 0, 0, 0);
        acc[mi][ni] = __builtin_amdgcn_mfma_f32_16x16x32_bf16(qa[mi], kb[ni], acc[mi][ni], 0, 0, 0);
      }
    }
  }
  const float scale = 0.125f;   // 1/sqrt(64)
  float* Wrow = Wout + ((size_t)bh * S_ + q0) * S_ + k0;
  const int rb = wm*64 + ((lane >> 4) << 2);
  if ((kt >> 1) < qt) {          // fully unmasked tile
    #pragma unroll
    for (int ni = 0; ni < 2; ++ni) {
      const int col = wn*32 + ni*16 + (lane & 15);
      #pragma unroll
      for (int mi = 0; mi < 4; ++mi) {
        #pragma unroll
        for (int j = 0; j < 4; ++j)
          Wrow[(size_t)(rb + mi*16 + j) * S_ + col] = acc[mi][ni][j] * scale;
      }
    }
  } else {                       // diagonal-crossing tile: per-element guard
    #pragma unroll
    for (int ni = 0; ni < 2; ++ni) {
      const int col = wn*32 + ni*16 + (lane & 15);
      const int kg = k0 + col;
      #pragma unroll
      for (int mi = 0; mi < 4; ++mi) {
        #pragma unroll
        for (int j = 0; j < 4; ++j) {
          const int row = rb + mi*16 + j;
          if (kg <= q0 + row)
            Wrow[(size_t)row * S_ + col] = acc[mi][ni][j] * scale;
        }
      }
    }
  }
}

// ---------------- softmax: in-place over each row, zeros above diagonal -----
__global__ __launch_bounds__(256) void softmax_kernel(float* __restrict__ Wbuf) {
  const int q = blockIdx.x;
  float* row = Wbuf + ((size_t)blockIdx.y * S_ + q) * S_;
  const int valid = q + 1;
  __shared__ float sbuf[4];
  float v[8];
  float lmax = -INFINITY;
  #pragma unroll
  for (int i = 0; i < 8; ++i) {
    int k = threadIdx.x + (i << 8);
    v[i] = (k < valid) ? row[k] : -INFINITY;
    lmax = fmaxf(lmax, v[i]);
  }
  float m = block_allreduce(lmax, true, sbuf);
  float lsum = 0.f;
  #pragma unroll
  for (int i = 0; i < 8; ++i) {
    int k = threadIdx.x + (i << 8);
    v[i] = (k < valid) ? __expf(v[i] - m) : 0.f;
    lsum += v[i];
  }
  float s = block_allreduce(lsum, false, sbuf);
  float inv = 1.f / s;
  #pragma unroll
  for (int i = 0; i < 8; ++i) {
    int k = threadIdx.x + (i << 8);
    row[k] = v[i] * inv;
  }
}

// ---------------- PV (MFMA bf16x3): attn = W @ V per head -------------------
// W fp32 reg-stage+split; V^T bf16 gload_lds. Output pre-split bf16.
__global__ __launch_bounds__(256) void pv_mfma_kernel(
    const float* __restrict__ Wbuf,
    const ushort* __restrict__ Vthi, const ushort* __restrict__ Vtlo,
    ushort* __restrict__ AtHi, ushort* __restrict__ AtLo)
{
  const int qt = blockIdx.x, h = blockIdx.y, b = blockIdx.z;
  const int q0 = qt * 128;
  __shared__ ushort Wh2[2][128][32], Wl2[2][128][32];
  __shared__ ushort Vh2[2][64][32],  Vl2[2][64][32];
  const int tid = threadIdx.x;
  const int lane = tid & 63, wid = tid >> 6;
  const int wm = wid >> 1, wn = wid & 1;   // wave tile: 64 q x 32 d
  f32x4 acc[4][2] = {};
  const size_t wbase = (((size_t)b * H_ + h) * S_ + q0) * S_;
  const ushort* vth = Vthi + ((size_t)(b*H_ + h)) * DH_ * S_;
  const ushort* vtl = Vtlo + ((size_t)(b*H_ + h)) * DH_ * S_;
  const int kf = (lane >> 4) << 3;
  const int fm = wm * 64 + (lane & 15);
  const int fn = wn * 32 + (lane & 15);
  const int nkt = 2*qt + 2;
  for (int kt = 0; kt < nkt; ++kt) {
    const int k0 = kt * 64;
    // V^T tiles via gload_lds first (overlaps with W split below)
    #pragma unroll
    for (int i = 0; i < 2; ++i) {
      int jj = wid * 128 + i * 64 + lane;
      int drow = (jj >> 2) & 63;
      int kk = ((jj >> 8) << 5) + ((jj & 3) << 3);
      gl16(vth + (size_t)drow * S_ + k0 + kk, (char*)&Vh2[0][0][0] + (unsigned)(jj - lane) * 16);
      gl16(vtl + (size_t)drow * S_ + k0 + kk, (char*)&Vl2[0][0][0] + (unsigned)(jj - lane) * 16);
    }
    // W: 128 q x 64 k fp32 -> split into k-halves
    #pragma unroll
    for (int i = 0; i < 8; ++i) {
      int idx = tid + (i << 8);
      int r = idx >> 4, c4 = (idx & 15) << 2;
      float4 v = *(const float4*)(Wbuf + wbase + (size_t)r * S_ + k0 + c4);
      ushort h0,h1,h2,h3,l0,l1,l2,l3;
      split2(v.x,h0,l0); split2(v.y,h1,l1); split2(v.z,h2,l2); split2(v.w,h3,l3);
      int hf = c4 >> 5, cl = c4 & 31;
      *(ushort4*)&Wh2[hf][r][cl] = make_ushort4(h0,h1,h2,h3);
      *(ushort4*)&Wl2[hf][r][cl] = make_ushort4(l0,l1,l2,l3);
    }
    __syncthreads();
    #pragma unroll
    for (int hf = 0; hf < 2; ++hf) {
      s16x8 wa[4], wb[4], va[2], vb[2];
      #pragma unroll
      for (int mi = 0; mi < 4; ++mi) {
        wa[mi] = *(const s16x8*)&Wh2[hf][fm + mi*16][kf];
        wb[mi] = *(const s16x8*)&Wl2[hf][fm + mi*16][kf];
      }
      #pragma unroll
      for (int ni = 0; ni < 2; ++ni) {
        va[ni] = *(const s16x8*)&Vh2[hf][fn + ni*16][kf];
        vb[ni] = *(const s16x8*)&Vl2[hf][fn + ni*16][kf];
      }
      #pragma unroll
      for (int mi = 0; mi < 4; ++mi) {
        #pragma unroll
        for (int ni = 0; ni < 2; ++ni) {
          acc[mi][ni] = __builtin_amdgcn_mfma_f32_16x16x32_bf16(wa[mi], va[ni], acc[mi][ni], 0, 0, 0);
          acc[mi][ni] = __builtin_amdgcn_mfma_f32_16x16x32_bf16(wb[mi], va[ni], acc[mi][ni], 0, 0, 0);
          acc[mi][ni] = __builtin_amdgcn_mfma_f32_16x16x32_bf16(wa[mi], vb[ni], acc[mi][ni], 0, 0, 0);
        }
      }
    }
    __syncthreads();
  }
  const int rb = q0 + wm*64 + ((lane >> 4) << 2);
  #pragma unroll
  for (int ni = 0; ni < 2; ++ni) {
    const int col = h * DH_ + wn*32 + ni*16 + (lane & 15);
    #pragma unroll
    for (int mi = 0; mi < 4; ++mi) {
      #pragma unroll
      for (int j = 0; j < 4; ++j) {
        size_t off = ((size_t)b * S_ + rb + mi*16 + j) * D_ + col;
        ushort hh, ll; split2(acc[mi][ni][j], hh, ll);
        AtHi[off] = hh; AtLo[off] = ll;
      }
    }
  }
}

// ---------------- LayerNorm over last dim (1024) ----------------------------
__global__ __launch_bounds__(256) void ln_kernel(
    const float* __restrict__ R, const float* __restrict__ gamma,
    const float* __restrict__ beta, float* __restrict__ Out)
{
  const int row = blockIdx.x;
  const float* x = R + (size_t)row * D_;
  __shared__ float sbuf[4];
  float4 xv = *(const float4*)(x + threadIdx.x * 4);
  float s  = xv.x + xv.y + xv.z + xv.w;
  float ss = xv.x*xv.x + xv.y*xv.y + xv.z*xv.z + xv.w*xv.w;
  float tot  = block_allreduce(s,  false, sbuf);
  float tot2 = block_allreduce(ss, false, sbuf);
  float mu  = tot  * (1.f / D_);
  float var = tot2 * (1.f / D_) - mu * mu;
  float inv = rsqrtf(var + LN_EPS);
  float4 g  = *(const float4*)(gamma + threadIdx.x * 4);
  float4 be = *(const float4*)(beta  + threadIdx.x * 4);
  float4 o;
  o.x = (xv.x - mu) * inv * g.x + be.x;
  o.y = (xv.y - mu) * inv * g.y + be.y;
  o.z = (xv.z - mu) * inv * g.z + be.z;
  o.w = (xv.w - mu) * inv * g.w + be.w;
  *(float4*)(Out + (size_t)row * D_ + threadIdx.x * 4) = o;
}

extern "C" void kernel_launch(void* const* d_in, const int* in_sizes, int n_in,
                              void* d_out, int out_size, void* d_ws, size_t ws_size,
                              hipStream_t stream) {
  const float* X     = (const float*)d_in[0];
  const float* Wq    = (const float*)d_in[1];
  const float* bq    = (const float*)d_in[2];
  const float* Wk    = (const float*)d_in[3];
  const float* bk    = (const float*)d_in[4];
  const float* Wv    = (const float*)d_in[5];
  const float* bv    = (const float*)d_in[6];
  const float* Wo    = (const float*)d_in[7];
  const float* bo    = (const float*)d_in[8];
  const float* gamma = (const float*)d_in[9];
  const float* beta  = (const float*)d_in[10];

  float* out     = (float*)d_out;
  float* normed  = out;
  float* weights = out + (size_t)B_ * S_ * D_;       // [B,H,S,S]

  const size_t sz = (size_t)B_ * S_ * D_;            // 8388608
  const size_t wsz = (size_t)D_ * D_;                // 1048576

  // ws as ushort pool: capacity 6*sz ushorts (= 3*sz floats)
  ushort* u = (ushort*)d_ws;
  ushort* Qhi  = u;            ushort* Qlo  = u + sz;
  ushort* Khi  = u + 2*sz;     ushort* Klo  = u + 3*sz;
  ushort* Vthi = u + 4*sz;     ushort* Vtlo = u + 5*sz;
  // after scores (Q/K dead):
  ushort* AtHi = u;            ushort* AtLo = u + sz;
  ushort* WoHi = u + 2*sz;     ushort* WoLo = WoHi + wsz;
  // after PV (Vt dead):
  float*  Resid = (float*)(u + 4*sz);

  // pre-scores scratch in the weights output region (dead until scores)
  ushort* w0   = (ushort*)weights;
  ushort* Xhi  = w0;           ushort* Xlo  = w0 + sz;
  ushort* WqHi = w0 + 2*sz;            ushort* WqLo = WqHi + wsz;
  ushort* WkHi = WqLo + wsz;           ushort* WkLo = WkHi + wsz;
  ushort* WvHi = WkLo + wsz;           ushort* WvLo = WvHi + wsz;
  ushort* Vhi  = WvLo + wsz;           ushort* Vlo  = Vhi + sz;

  dim3 blk(256);
  dim3 gg(D_ / 128, M_ / 128);                       // (8, 64)
  dim3 sg(sz / 2048);                                // 4096 blocks

  split_kernel <<<sg, blk, 0, stream>>>(X, Xhi, Xlo);
  splitT_kernel<<<dim3(16,16), blk, 0, stream>>>(Wq, WqHi, WqLo);
  splitT_kernel<<<dim3(16,16), blk, 0, stream>>>(Wk, WkHi, WkLo);
  splitT_kernel<<<dim3(16,16), blk, 0, stream>>>(Wv, WvHi, WvLo);

  gemm_mfma_kernel<<<gg, blk, 0, stream>>>(Xhi, Xlo, WqHi, WqLo, bq, nullptr,
                                           nullptr, Qhi, Qlo, M_, D_, D_);
  gemm_mfma_kernel<<<gg, blk, 0, stream>>>(Xhi, Xlo, WkHi, WkLo, bk, nullptr,
                                           nullptr, Khi, Klo, M_, D_, D_);
  gemm_mfma_kernel<<<gg, blk, 0, stream>>>(Xhi, Xlo, WvHi, WvLo, bv, nullptr,
                                           nullptr, Vhi, Vlo, M_, D_, D_);

  vtrans_kernel<<<dim3(S_/64, H_, B_), blk, 0, stream>>>(Vhi, Vlo, Vthi, Vtlo);

  scores_mfma_kernel<<<dim3(S_/64, S_/128, B_*H_), blk, 0, stream>>>(
      Qhi, Qlo, Khi, Klo, weights);
  softmax_kernel<<<dim3(S_, B_*H_), blk, 0, stream>>>(weights);
  pv_mfma_kernel<<<dim3(S_/128, H_, B_), blk, 0, stream>>>(
      weights, Vthi, Vtlo, AtHi, AtLo);

  splitT_kernel<<<dim3(16,16), blk, 0, stream>>>(Wo, WoHi, WoLo);
  gemm_mfma_kernel<<<gg, blk, 0, stream>>>(AtHi, AtLo, WoHi, WoLo, bo, X,
                                           Resid, nullptr, nullptr, M_, D_, D_);

  ln_kernel<<<dim3(M_), blk, 0, stream>>>(Resid, gamma, beta, normed);
}

// Round 4
// 2023.648 us; speedup vs baseline: 1.1126x; 1.1126x over previous
//
#include <hip/hip_runtime.h>
#include <math.h>

#define B_  4
#define S_  2048
#define D_  1024
#define H_  16
#define DH_ 64
#define M_  (B_*S_)          // 8192
#define LN_EPS 1e-6f

typedef __attribute__((ext_vector_type(4))) float f32x4;
typedef __attribute__((ext_vector_type(8))) short s16x8;   // 8 bf16 = 4 VGPRs

// ---------------- async global->LDS, 16 B per lane --------------------------
__device__ __forceinline__ void gl16(const void* g, void* l) {
  __builtin_amdgcn_global_load_lds(
      (const __attribute__((address_space(1))) unsigned int*)g,
      (__attribute__((address_space(3))) unsigned int*)l, 16, 0, 0);
}

// ---------------- fp32 -> bf16(hi) + bf16(lo) split (truncation) ------------
__device__ __forceinline__ void split2(float x, ushort& h, ushort& l) {
  unsigned u = __float_as_uint(x);
  h = (ushort)(u >> 16);
  float r = x - __uint_as_float(u & 0xFFFF0000u);   // exact
  l = (ushort)(__float_as_uint(r) >> 16);
}

// Elementwise split: in [n] fp32 -> hi,lo [n] bf16. 8 elems/thread.
__global__ __launch_bounds__(256) void split_kernel(
    const float* __restrict__ in, ushort* __restrict__ hi, ushort* __restrict__ lo)
{
  const size_t t = (size_t)blockIdx.x * 256 + threadIdx.x;
  const float4 a = *(const float4*)(in + t * 8);
  const float4 b = *(const float4*)(in + t * 8 + 4);
  s16x8 hv, lv;
  ushort h, l;
  split2(a.x, h, l); hv[0] = (short)h; lv[0] = (short)l;
  split2(a.y, h, l); hv[1] = (short)h; lv[1] = (short)l;
  split2(a.z, h, l); hv[2] = (short)h; lv[2] = (short)l;
  split2(a.w, h, l); hv[3] = (short)h; lv[3] = (short)l;
  split2(b.x, h, l); hv[4] = (short)h; lv[4] = (short)l;
  split2(b.y, h, l); hv[5] = (short)h; lv[5] = (short)l;
  split2(b.z, h, l); hv[6] = (short)h; lv[6] = (short)l;
  split2(b.w, h, l); hv[7] = (short)h; lv[7] = (short)l;
  *(s16x8*)(hi + t * 8) = hv;
  *(s16x8*)(lo + t * 8) = lv;
}

// Transpose + split: W [K=1024][N=1024] fp32 -> hiT,loT [N][K] bf16.
__global__ __launch_bounds__(256) void splitT_kernel(
    const float* __restrict__ W, ushort* __restrict__ hiT, ushort* __restrict__ loT)
{
  __shared__ float tile[64][65];
  const int n0 = blockIdx.x * 64, k0 = blockIdx.y * 64;
  const int tid = threadIdx.x;
  #pragma unroll
  for (int i = 0; i < 4; ++i) {
    int c = tid + (i << 8);
    int r = c >> 4;
    int c4 = (c & 15) << 2;
    float4 v = *(const float4*)(W + (size_t)(k0 + r) * D_ + n0 + c4);
    tile[r][c4+0] = v.x; tile[r][c4+1] = v.y; tile[r][c4+2] = v.z; tile[r][c4+3] = v.w;
  }
  __syncthreads();
  #pragma unroll
  for (int i = 0; i < 4; ++i) {
    int c = tid + (i << 8);
    int n = c >> 4;
    int k4 = (c & 15) << 2;
    ushort h0,h1,h2,h3, l0,l1,l2,l3;
    split2(tile[k4+0][n], h0, l0);
    split2(tile[k4+1][n], h1, l1);
    split2(tile[k4+2][n], h2, l2);
    split2(tile[k4+3][n], h3, l3);
    size_t o = (size_t)(n0 + n) * D_ + k0 + k4;
    *(ushort4*)(hiT + o) = make_ushort4(h0, h1, h2, h3);
    *(ushort4*)(loT + o) = make_ushort4(l0, l1, l2, l3);
  }
}

// ---------------- bf16x3 MFMA GEMM: gload_lds staged, fp32 epilogue ---------
// A as Ahi/Alo [M][K] bf16; B as BThi/BTlo [N][K] bf16 (pre-transposed).
// Tile 128x128, BK=32, 4 waves (2x2). C = A@B + bias (+resid), fp32 out.
__global__ __launch_bounds__(256) void gemm_mfma_kernel(
    const ushort* __restrict__ Ahi, const ushort* __restrict__ Alo,
    const ushort* __restrict__ BThi, const ushort* __restrict__ BTlo,
    const float* __restrict__ bias, const float* __restrict__ resid,
    float* __restrict__ C, int M, int N, int K)
{
  __shared__ ushort Ah[128][32], Al[128][32], Bh[128][32], Bl[128][32];
  const int tid  = threadIdx.x;
  const int lane = tid & 63;
  const int wid  = tid >> 6;
  const int wm   = wid >> 1, wn = wid & 1;
  const int bm = blockIdx.y * 128, bn = blockIdx.x * 128;

  // staging chunks: j in [0,512), row=j>>2, kc=(j&3)*8 elems
  const int j0 = wid * 128 + lane, j1 = j0 + 64;
  const int r0 = j0 >> 2, kc0 = (j0 & 3) << 3;
  const int r1 = j1 >> 2, kc1 = (j1 & 3) << 3;
  const unsigned off0 = (unsigned)(wid * 128) * 16;   // wave-uniform LDS byte
  const unsigned off1 = off0 + 1024;

  const ushort* a0  = Ahi  + (size_t)(bm + r0) * K + kc0;
  const ushort* a1  = Ahi  + (size_t)(bm + r1) * K + kc1;
  const ushort* c0  = Alo  + (size_t)(bm + r0) * K + kc0;
  const ushort* c1  = Alo  + (size_t)(bm + r1) * K + kc1;
  const ushort* b0  = BThi + (size_t)(bn + r0) * K + kc0;
  const ushort* b1  = BThi + (size_t)(bn + r1) * K + kc1;
  const ushort* d0p = BTlo + (size_t)(bn + r0) * K + kc0;
  const ushort* d1p = BTlo + (size_t)(bn + r1) * K + kc1;

  f32x4 acc[4][4] = {};
  const int kf = (lane >> 4) << 3;
  const int fm = wm * 64 + (lane & 15);
  const int fn = wn * 64 + (lane & 15);

  for (int k0 = 0; k0 < K; k0 += 32) {
    gl16(a0 + k0,  (char*)&Ah[0][0] + off0);
    gl16(a1 + k0,  (char*)&Ah[0][0] + off1);
    gl16(c0 + k0,  (char*)&Al[0][0] + off0);
    gl16(c1 + k0,  (char*)&Al[0][0] + off1);
    gl16(b0 + k0,  (char*)&Bh[0][0] + off0);
    gl16(b1 + k0,  (char*)&Bh[0][0] + off1);
    gl16(d0p + k0, (char*)&Bl[0][0] + off0);
    gl16(d1p + k0, (char*)&Bl[0][0] + off1);
    __syncthreads();
    s16x8 ah[4], al[4], bh[4], bl[4];
    #pragma unroll
    for (int i = 0; i < 4; ++i) {
      ah[i] = *(const s16x8*)&Ah[fm + i*16][kf];
      al[i] = *(const s16x8*)&Al[fm + i*16][kf];
      bh[i] = *(const s16x8*)&Bh[fn + i*16][kf];
      bl[i] = *(const s16x8*)&Bl[fn + i*16][kf];
    }
    #pragma unroll
    for (int mi = 0; mi < 4; ++mi) {
      #pragma unroll
      for (int ni = 0; ni < 4; ++ni) {
        acc[mi][ni] = __builtin_amdgcn_mfma_f32_16x16x32_bf16(ah[mi], bh[ni], acc[mi][ni], 0, 0, 0);
        acc[mi][ni] = __builtin_amdgcn_mfma_f32_16x16x32_bf16(al[mi], bh[ni], acc[mi][ni], 0, 0, 0);
        acc[mi][ni] = __builtin_amdgcn_mfma_f32_16x16x32_bf16(ah[mi], bl[ni], acc[mi][ni], 0, 0, 0);
      }
    }
    __syncthreads();
  }
  const int rbase = bm + wm*64 + ((lane >> 4) << 2);
  #pragma unroll
  for (int ni = 0; ni < 4; ++ni) {
    const int col = bn + wn*64 + ni*16 + (lane & 15);
    const float bb = bias[col];
    #pragma unroll
    for (int mi = 0; mi < 4; ++mi) {
      #pragma unroll
      for (int j = 0; j < 4; ++j) {
        const int row = rbase + mi*16 + j;
        float v = acc[mi][ni][j] + bb;
        if (resid) v += resid[(size_t)row * N + col];
        C[(size_t)row * N + col] = v;
      }
    }
  }
}

// ---------------- fused causal attention (flash 2-pass) ---------------------
// Block: 64 q-rows of one (b,h). Wave w owns rows w*16..w*16+15.
// Pass A: online softmax + PV accumulate. Pass B: recompute S, write weights.
// K LDS buffer is reused for P between QK^T and PV. Pads=72 (144B=16B-mult
// rows -> b128 frag reads, 2-way bank aliasing = free).
__global__ __launch_bounds__(256) void attn_fused_kernel(
    const float* Q, const float* __restrict__ Kg, const float* __restrict__ Vg,
    float* __restrict__ Wout, float* Attn)
{
  const int qt = blockIdx.x, h = blockIdx.y, b = blockIdx.z;
  const int q0 = qt * 64;
  __shared__ ushort Kh[64][72], Kl[64][72];   // K tile; reused as P tile
  __shared__ ushort Vh[64][72], Vl[64][72];   // V^T tile [d][k]
  const int tid = threadIdx.x;
  const int lane = tid & 63, w = tid >> 6;
  const int l15 = lane & 15, lg = lane >> 4;
  const int kf = lg << 3;

  // Q fragments -> registers (persist across both passes)
  const float* Qrow = Q + ((size_t)(b * S_ + q0 + w*16 + l15)) * D_ + h * DH_;
  s16x8 qh[2], ql[2];
  #pragma unroll
  for (int hd = 0; hd < 2; ++hd) {
    float x[8];
    *(float4*)&x[0] = *(const float4*)(Qrow + hd*32 + kf);
    *(float4*)&x[4] = *(const float4*)(Qrow + hd*32 + kf + 4);
    #pragma unroll
    for (int e = 0; e < 8; ++e) {
      ushort hh, ll; split2(x[e], hh, ll);
      qh[hd][e] = (short)hh; ql[hd][e] = (short)ll;
    }
  }

  float mrow[4], lrow[4];
  #pragma unroll
  for (int j = 0; j < 4; ++j) { mrow[j] = -INFINITY; lrow[j] = 0.f; }
  f32x4 acc[4] = {};   // PV accumulator: [nd] d-frags x 4 rows

  const float* Kbase = Kg + (size_t)b * S_ * D_ + h * DH_;
  const float* Vbase = Vg + (size_t)b * S_ * D_ + h * DH_;
  const int nkt = qt + 1;

  // ---------------- pass A ----------------
  for (int kt = 0; kt < nkt; ++kt) {
    const int k0 = kt * 64;
    __syncthreads();                       // prev-iter V/P reads done
    #pragma unroll
    for (int i = 0; i < 4; ++i) {          // stage K + V^T (split in-kernel)
      int idx = tid + (i << 8);
      int r = idx >> 4, c4 = (idx & 15) << 2;
      float4 kv = *(const float4*)(Kbase + (size_t)(k0 + r) * D_ + c4);
      ushort h0,h1,h2,h3,l0,l1,l2,l3;
      split2(kv.x,h0,l0); split2(kv.y,h1,l1); split2(kv.z,h2,l2); split2(kv.w,h3,l3);
      *(ushort4*)&Kh[r][c4] = make_ushort4(h0,h1,h2,h3);
      *(ushort4*)&Kl[r][c4] = make_ushort4(l0,l1,l2,l3);
      float4 vv = *(const float4*)(Vbase + (size_t)(k0 + r) * D_ + c4);
      split2(vv.x,h0,l0); split2(vv.y,h1,l1); split2(vv.z,h2,l2); split2(vv.w,h3,l3);
      Vh[c4+0][r]=h0; Vh[c4+1][r]=h1; Vh[c4+2][r]=h2; Vh[c4+3][r]=h3;
      Vl[c4+0][r]=l0; Vl[c4+1][r]=l1; Vl[c4+2][r]=l2; Vl[c4+3][r]=l3;
    }
    __syncthreads();
    f32x4 s[4] = {};                       // QK^T: 16q x 64k per wave
    #pragma unroll
    for (int hd = 0; hd < 2; ++hd) {
      #pragma unroll
      for (int ni = 0; ni < 4; ++ni) {
        s16x8 ka = *(const s16x8*)&Kh[ni*16 + l15][hd*32 + kf];
        s16x8 kb = *(const s16x8*)&Kl[ni*16 + l15][hd*32 + kf];
        s[ni] = __builtin_amdgcn_mfma_f32_16x16x32_bf16(qh[hd], ka, s[ni], 0, 0, 0);
        s[ni] = __builtin_amdgcn_mfma_f32_16x16x32_bf16(ql[hd], ka, s[ni], 0, 0, 0);
        s[ni] = __builtin_amdgcn_mfma_f32_16x16x32_bf16(qh[hd], kb, s[ni], 0, 0, 0);
      }
    }
    __syncthreads();                       // all K reads done; K buf becomes P
    const bool diag = (kt == qt);
    float sv[4][4];
    #pragma unroll
    for (int ni = 0; ni < 4; ++ni) {
      #pragma unroll
      for (int j = 0; j < 4; ++j) {
        float x = s[ni][j] * 0.125f;       // 1/sqrt(64)
        if (diag && (ni*16 + l15 > w*16 + lg*4 + j)) x = -INFINITY;
        sv[ni][j] = x;
      }
    }
    float fac[4];
    #pragma unroll
    for (int j = 0; j < 4; ++j) {          // row max (over 64 cols)
      float t = fmaxf(fmaxf(sv[0][j], sv[1][j]), fmaxf(sv[2][j], sv[3][j]));
      #pragma unroll
      for (int o = 1; o < 16; o <<= 1) t = fmaxf(t, __shfl_xor(t, o, 64));
      float mn = fmaxf(mrow[j], t);
      fac[j] = __expf(mrow[j] - mn);       // first tile: exp(-inf)=0
      mrow[j] = mn;
    }
    float p[4][4];
    #pragma unroll
    for (int ni = 0; ni < 4; ++ni)
      #pragma unroll
      for (int j = 0; j < 4; ++j)
        p[ni][j] = __expf(sv[ni][j] - mrow[j]);   // masked -inf -> 0
    #pragma unroll
    for (int j = 0; j < 4; ++j) {          // row sum
      float su = p[0][j] + p[1][j] + p[2][j] + p[3][j];
      #pragma unroll
      for (int o = 1; o < 16; o <<= 1) su += __shfl_xor(su, o, 64);
      lrow[j] = lrow[j] * fac[j] + su;
    }
    #pragma unroll
    for (int nd = 0; nd < 4; ++nd)
      #pragma unroll
      for (int j = 0; j < 4; ++j)
        acc[nd][j] *= fac[j];
    #pragma unroll
    for (int ni = 0; ni < 4; ++ni)         // P -> LDS (own rows; K buf reuse)
      #pragma unroll
      for (int j = 0; j < 4; ++j) {
        ushort hh, ll; split2(p[ni][j], hh, ll);
        Kh[w*16 + lg*4 + j][ni*16 + l15] = hh;
        Kl[w*16 + lg*4 + j][ni*16 + l15] = ll;
      }
    #pragma unroll
    for (int hd = 0; hd < 2; ++hd) {       // PV: acc += P @ V
      s16x8 pa = *(const s16x8*)&Kh[w*16 + l15][hd*32 + kf];
      s16x8 pb = *(const s16x8*)&Kl[w*16 + l15][hd*32 + kf];
      #pragma unroll
      for (int nd = 0; nd < 4; ++nd) {
        s16x8 va = *(const s16x8*)&Vh[nd*16 + l15][hd*32 + kf];
        s16x8 vb = *(const s16x8*)&Vl[nd*16 + l15][hd*32 + kf];
        acc[nd] = __builtin_amdgcn_mfma_f32_16x16x32_bf16(pa, va, acc[nd], 0, 0, 0);
        acc[nd] = __builtin_amdgcn_mfma_f32_16x16x32_bf16(pb, va, acc[nd], 0, 0, 0);
        acc[nd] = __builtin_amdgcn_mfma_f32_16x16x32_bf16(pa, vb, acc[nd], 0, 0, 0);
      }
    }
  }

  float invl[4];
  #pragma unroll
  for (int j = 0; j < 4; ++j) invl[j] = 1.f / lrow[j];
  #pragma unroll
  for (int nd = 0; nd < 4; ++nd)           // Attn out (fp32)
    #pragma unroll
    for (int j = 0; j < 4; ++j)
      Attn[((size_t)(b * S_ + q0 + w*16 + lg*4 + j)) * D_ + h * DH_ + nd*16 + l15]
          = acc[nd][j] * invl[j];

  // ---------------- pass B: recompute S, write normalized weights ----------
  float* Wrow = Wout + (((size_t)(b * H_ + h)) * S_ + q0) * S_;
  for (int kt = 0; kt < nkt; ++kt) {
    const int k0 = kt * 64;
    __syncthreads();
    #pragma unroll
    for (int i = 0; i < 4; ++i) {          // stage K only
      int idx = tid + (i << 8);
      int r = idx >> 4, c4 = (idx & 15) << 2;
      float4 kv = *(const float4*)(Kbase + (size_t)(k0 + r) * D_ + c4);
      ushort h0,h1,h2,h3,l0,l1,l2,l3;
      split2(kv.x,h0,l0); split2(kv.y,h1,l1); split2(kv.z,h2,l2); split2(kv.w,h3,l3);
      *(ushort4*)&Kh[r][c4] = make_ushort4(h0,h1,h2,h3);
      *(ushort4*)&Kl[r][c4] = make_ushort4(l0,l1,l2,l3);
    }
    __syncthreads();
    f32x4 s[4] = {};
    #pragma unroll
    for (int hd = 0; hd < 2; ++hd) {
      #pragma unroll
      for (int ni = 0; ni < 4; ++ni) {
        s16x8 ka = *(const s16x8*)&Kh[ni*16 + l15][hd*32 + kf];
        s16x8 kb = *(const s16x8*)&Kl[ni*16 + l15][hd*32 + kf];
        s[ni] = __builtin_amdgcn_mfma_f32_16x16x32_bf16(qh[hd], ka, s[ni], 0, 0, 0);
        s[ni] = __builtin_amdgcn_mfma_f32_16x16x32_bf16(ql[hd], ka, s[ni], 0, 0, 0);
        s[ni] = __builtin_amdgcn_mfma_f32_16x16x32_bf16(qh[hd], kb, s[ni], 0, 0, 0);
      }
    }
    const bool diag = (kt == qt);
    #pragma unroll
    for (int ni = 0; ni < 4; ++ni) {
      #pragma unroll
      for (int j = 0; j < 4; ++j) {
        float x = s[ni][j] * 0.125f;
        float wv;
        if (diag && (ni*16 + l15 > w*16 + lg*4 + j)) wv = 0.f;   // exact zero
        else wv = __expf(x - mrow[j]) * invl[j];
        Wrow[(size_t)(w*16 + lg*4 + j) * S_ + k0 + ni*16 + l15] = wv;
      }
    }
  }
  // fully-masked tiles: exact zeros
  for (int kt = nkt; kt < S_/64; ++kt) {
    const int k0 = kt * 64;
    #pragma unroll
    for (int i = 0; i < 4; ++i) {
      int idx = tid + (i << 8);
      int r = idx >> 4, c4 = (idx & 15) << 2;
      float4 z = {0.f, 0.f, 0.f, 0.f};
      *(float4*)(Wrow + (size_t)r * S_ + k0 + c4) = z;
    }
  }
}

// ---------------- block-wide all-reduce (256 threads = 4 waves of 64) -------
__device__ __forceinline__ float block_allreduce(float v, bool is_max, float* sbuf) {
  #pragma unroll
  for (int o = 32; o > 0; o >>= 1) {
    float other = __shfl_down(v, o, 64);
    v = is_max ? fmaxf(v, other) : (v + other);
  }
  __syncthreads();
  if ((threadIdx.x & 63) == 0) sbuf[threadIdx.x >> 6] = v;
  __syncthreads();
  float r = sbuf[0];
  #pragma unroll
  for (int w = 1; w < 4; ++w) r = is_max ? fmaxf(r, sbuf[w]) : (r + sbuf[w]);
  return r;
}

// ---------------- LayerNorm over last dim (1024) ----------------------------
__global__ __launch_bounds__(256) void ln_kernel(
    const float* __restrict__ R, const float* __restrict__ gamma,
    const float* __restrict__ beta, float* __restrict__ Out)
{
  const int row = blockIdx.x;
  const float* x = R + (size_t)row * D_;
  __shared__ float sbuf[4];
  float4 xv = *(const float4*)(x + threadIdx.x * 4);
  float s  = xv.x + xv.y + xv.z + xv.w;
  float ss = xv.x*xv.x + xv.y*xv.y + xv.z*xv.z + xv.w*xv.w;
  float tot  = block_allreduce(s,  false, sbuf);
  float tot2 = block_allreduce(ss, false, sbuf);
  float mu  = tot  * (1.f / D_);
  float var = tot2 * (1.f / D_) - mu * mu;
  float inv = rsqrtf(var + LN_EPS);
  float4 g  = *(const float4*)(gamma + threadIdx.x * 4);
  float4 be = *(const float4*)(beta  + threadIdx.x * 4);
  float4 o;
  o.x = (xv.x - mu) * inv * g.x + be.x;
  o.y = (xv.y - mu) * inv * g.y + be.y;
  o.z = (xv.z - mu) * inv * g.z + be.z;
  o.w = (xv.w - mu) * inv * g.w + be.w;
  *(float4*)(Out + (size_t)row * D_ + threadIdx.x * 4) = o;
}

extern "C" void kernel_launch(void* const* d_in, const int* in_sizes, int n_in,
                              void* d_out, int out_size, void* d_ws, size_t ws_size,
                              hipStream_t stream) {
  const float* X     = (const float*)d_in[0];
  const float* Wq    = (const float*)d_in[1];
  const float* bq    = (const float*)d_in[2];
  const float* Wk    = (const float*)d_in[3];
  const float* bk    = (const float*)d_in[4];
  const float* Wv    = (const float*)d_in[5];
  const float* bv    = (const float*)d_in[6];
  const float* Wo    = (const float*)d_in[7];
  const float* bo    = (const float*)d_in[8];
  const float* gamma = (const float*)d_in[9];
  const float* beta  = (const float*)d_in[10];

  float* out     = (float*)d_out;
  float* normed  = out;
  float* weights = out + (size_t)B_ * S_ * D_;       // [B,H,S,S]

  const size_t sz = (size_t)B_ * S_ * D_;            // 8388608
  const size_t wsz = (size_t)D_ * D_;                // 1048576

  float* ws   = (float*)d_ws;
  float* Qb   = ws;
  float* Kb   = ws + sz;
  float* Vb   = ws + 2 * sz;
  float* Attn  = Qb;   // fused kernel: each block reads only its own Q slice
                       // (into regs at start) and writes only that slice.
  float* Resid = Kb;   // K dead after fused kernel

  // phase-1 bf16 scratch in weights output region (dead until fused kernel,
  // which runs after all its consumers)
  ushort* w0   = (ushort*)weights;
  ushort* Xhi  = w0;           ushort* Xlo  = w0 + sz;
  ushort* WqHi = w0 + 2*sz;    ushort* WqLo = WqHi + wsz;
  ushort* WkHi = WqLo + wsz;   ushort* WkLo = WkHi + wsz;
  ushort* WvHi = WkLo + wsz;   ushort* WvLo = WvHi + wsz;
  // late-phase scratch in ws
  ushort* AtHi = (ushort*)Vb;  ushort* AtLo = AtHi + sz;   // V dead after fused
  ushort* WoHi = (ushort*)Qb;  ushort* WoLo = WoHi + wsz;  // Attn dead after split

  dim3 blk(256);
  dim3 gg(D_ / 128, M_ / 128);                       // (8, 64)
  dim3 sg(sz / 2048);                                // 4096 blocks

  split_kernel <<<sg, blk, 0, stream>>>(X, Xhi, Xlo);
  splitT_kernel<<<dim3(16,16), blk, 0, stream>>>(Wq, WqHi, WqLo);
  splitT_kernel<<<dim3(16,16), blk, 0, stream>>>(Wk, WkHi, WkLo);
  splitT_kernel<<<dim3(16,16), blk, 0, stream>>>(Wv, WvHi, WvLo);

  gemm_mfma_kernel<<<gg, blk, 0, stream>>>(Xhi, Xlo, WqHi, WqLo, bq, nullptr, Qb, M_, D_, D_);
  gemm_mfma_kernel<<<gg, blk, 0, stream>>>(Xhi, Xlo, WkHi, WkLo, bk, nullptr, Kb, M_, D_, D_);
  gemm_mfma_kernel<<<gg, blk, 0, stream>>>(Xhi, Xlo, WvHi, WvLo, bv, nullptr, Vb, M_, D_, D_);

  attn_fused_kernel<<<dim3(S_/64, H_, B_), blk, 0, stream>>>(Qb, Kb, Vb, weights, Attn);

  split_kernel <<<sg, blk, 0, stream>>>(Attn, AtHi, AtLo);
  splitT_kernel<<<dim3(16,16), blk, 0, stream>>>(Wo, WoHi, WoLo);
  gemm_mfma_kernel<<<gg, blk, 0, stream>>>(AtHi, AtLo, WoHi, WoLo, bo, X, Resid, M_, D_, D_);

  ln_kernel<<<dim3(M_), blk, 0, stream>>>(Resid, gamma, beta, normed);
}